// Round 1
// baseline (395.221 us; speedup 1.0000x reference)
//
#include <hip/hip_runtime.h>

// CTC batch cost forward (keras ctc_batch_cost port), B=256, T=256, C=1000, L=64.
// One block per batch row; S=2L+1=129 states live in threads 0..128 of a
// 192-thread block. Alpha kept in LDS double buffer, 1 barrier per t-step.
// Emission probs gathered directly from y_pred with 2x4 register-group
// prefetch (vmcnt depth up to 8) to hide HBM gather latency.

#define T_   256
#define C_   1000
#define L_   64
#define S_   129        // 2*L+1
#define BLANK 999       // C-1
#define NEGF (-1e30f)
#define EPSF (1e-7f)

__device__ __forceinline__ float lae2(float a, float b) {
    float m = fmaxf(a, b);
    return m + __logf(__expf(a - m) + __expf(b - m));
}

__global__ __launch_bounds__(192)
void ctc_fwd_kernel(const int* __restrict__ y_true,
                    const float* __restrict__ y_pred,
                    float* __restrict__ out) {
    const int b = blockIdx.x;
    const int s = threadIdx.x;

    __shared__ float buf[2][S_ + 3];
    __shared__ int   lab[L_];

    if (s < L_) lab[s] = y_true[b * L_ + s];
    __syncthreads();

    const float* __restrict__ yp = y_pred + (size_t)b * T_ * C_;

    // Extended-symbol column for this state, and skip-transition permission.
    int  extlab = BLANK;
    bool allow  = false;
    if (s < S_ && (s & 1)) {
        extlab = lab[s >> 1];
        allow  = (s >= 3) && (extlab != lab[(s >> 1) - 1]);
    }

    // t = 0 init: alpha[0] = lp(blank), alpha[1] = lp(lab0), else NEG.
    if (s < S_) {
        float a = NEGF;
        if (s == 0) a = __logf(yp[BLANK]  + EPSF);
        if (s == 1) a = __logf(yp[extlab] + EPSF);
        buf[0][s] = a;
    }
    int cur = 0;

    // Prefetch machinery: two register groups of 4 raw prob values each.
    float gA[4], gB[4];

    auto loadG = [&](float (&g)[4], int tb) {
        #pragma unroll
        for (int i = 0; i < 4; ++i) {
            int t = tb + i;
            if (t > T_ - 1) t = T_ - 1;          // clamped dummy load (cached)
            g[i] = (s < S_) ? yp[t * C_ + extlab] : 0.0f;
        }
    };
    auto consume = [&](float (&g)[4], int tb) {
        #pragma unroll
        for (int i = 0; i < 4; ++i) {
            int t = tb + i;
            if (t < T_) {                        // uniform across block
                __syncthreads();                 // buf[cur] writes visible
                if (s < S_) {
                    float a  = buf[cur][s];
                    float a1 = (s >= 1) ? buf[cur][s - 1] : NEGF;
                    float a2 = (s >= 2 && allow) ? buf[cur][s - 2] : NEGF;
                    float m  = fmaxf(fmaxf(a, a1), a2);
                    float r  = __expf(a - m) + __expf(a1 - m) + __expf(a2 - m);
                    float lp = __logf(g[i] + EPSF);
                    buf[cur ^ 1][s] = m + __logf(r) + lp;
                }
                cur ^= 1;
            }
        }
    };

    loadG(gA, 1);
    for (int t0 = 1; t0 < T_; t0 += 8) {
        loadG(gB, t0 + 4);
        consume(gA, t0);
        loadG(gA, t0 + 8);
        consume(gB, t0 + 4);
    }

    __syncthreads();
    if (s == 0) {
        // loss = -logaddexp(alpha[S-1], alpha[S-2])
        out[b] = -lae2(buf[cur][S_ - 1], buf[cur][S_ - 2]);
    }
}

extern "C" void kernel_launch(void* const* d_in, const int* in_sizes, int n_in,
                              void* d_out, int out_size, void* d_ws, size_t ws_size,
                              hipStream_t stream) {
    const int*   y_true = (const int*)d_in[0];
    const float* y_pred = (const float*)d_in[1];
    float*       out    = (float*)d_out;
    (void)in_sizes; (void)n_in; (void)d_ws; (void)ws_size; (void)out_size;

    ctc_fwd_kernel<<<dim3(256), dim3(192), 0, stream>>>(y_true, y_pred, out);
}

// Round 2
// 382.755 us; speedup vs baseline: 1.0326x; 1.0326x over previous
//
#include <hip/hip_runtime.h>

// CTC batch cost forward (keras ctc_batch_cost port), B=256, T=256, C=1000, L=64.
// ROUND 2: single-wave-per-row formulation, ZERO barriers in the t-loop.
// Lane i holds alpha[2i] (blank state) and alpha[2i+1] (label state lab[i]);
// alpha[128] is a third register, lane-63-local by construction.
// Per step the only cross-lane traffic is one __shfl_up of the odd alphas.
// Emission probs gathered with an 8-step-deep register prefetch ring —
// with no __syncthreads, the compiler's fine-grained vmcnt waits keep
// ~16 loads in flight per wave, hiding the scattered-gather HBM latency.

#define T_    256
#define C_    1000
#define L_    64
#define BLANK 999       // C-1
#define NEGF  (-1e30f)
#define EPSF  (1e-7f)
#define PD    8         // prefetch depth (t-steps)

__global__ __launch_bounds__(64)
void ctc_fwd_kernel(const int* __restrict__ y_true,
                    const float* __restrict__ y_pred,
                    float* __restrict__ out) {
    const int b    = blockIdx.x;
    const int lane = threadIdx.x;      // 0..63

    const float* __restrict__ yp = y_pred + (size_t)b * T_ * C_;

    // This lane's label (column for odd state 2*lane+1) and skip permission.
    const int lab   = y_true[b * L_ + lane];
    const int labm1 = __shfl_up(lab, 1, 64);
    const bool allow = (lane > 0) && (lab != labm1);

    // t = 0 init: alpha[0]=lp(blank), alpha[1]=lp(lab[0]), rest NEG.
    float aE, aO, aL;    // alpha[2i], alpha[2i+1], alpha[128]
    {
        float pb = yp[BLANK];
        float pl = yp[lab];
        aE = (lane == 0) ? __logf(pb + EPSF) : NEGF;
        aO = (lane == 0) ? __logf(pl + EPSF) : NEGF;
        aL = NEGF;
    }

    // Prefetch ring: raw probs for t = 1..PD.
    float pbB[PD], pbL[PD];
    #pragma unroll
    for (int k = 0; k < PD; ++k) {
        int t = 1 + k; if (t > T_ - 1) t = T_ - 1;
        const float* p = yp + t * C_;
        pbB[k] = p[BLANK];
        pbL[k] = p[lab];
    }

    for (int tb = 1; tb < T_; tb += PD) {
        #pragma unroll
        for (int j = 0; j < PD; ++j) {
            const int t = tb + j;
            if (t >= T_) break;                      // uniform across wave

            // Issue refill load for t+PD (clamped; clamp dups are L1-hot).
            int tn = t + PD; if (tn > T_ - 1) tn = T_ - 1;
            const float* pn = yp + tn * C_;
            float nB = pn[BLANK];
            float nL = pn[lab];

            const float lpB = __logf(pbB[j] + EPSF);
            const float lpL = __logf(pbL[j] + EPSF);

            // Cross-lane: alpha_old[2i-1] from lane i-1.
            float upO = __shfl_up(aO, 1, 64);
            if (lane == 0) upO = NEGF;

            // s = 2i (blank): from {2i, 2i-1}, no skip.
            float mE = fmaxf(aE, upO);
            float nE = mE + __logf(__expf(aE - mE) + __expf(upO - mE)) + lpB;

            // s = 2i+1 (label): from {2i+1, 2i, 2i-1 if allowed}.
            float sk = allow ? upO : NEGF;
            float mO = fmaxf(fmaxf(aO, aE), sk);
            float nO = mO + __logf(__expf(aO - mO) + __expf(aE - mO) +
                                   __expf(sk - mO)) + lpL;

            // s = 128 (blank, lane-63 local): from {128, 127}.
            float mL = fmaxf(aL, aO);
            float nL2 = mL + __logf(__expf(aL - mL) + __expf(aO - mL)) + lpB;

            aE = nE; aO = nO; aL = nL2;
            pbB[j] = nB; pbL[j] = nL;
        }
    }

    // loss = -logaddexp(alpha[S-1]=aL, alpha[S-2]=aO) at lane 63.
    if (lane == 63) {
        float m = fmaxf(aL, aO);
        out[b] = -(m + __logf(__expf(aL - m) + __expf(aO - m)));
    }
}

extern "C" void kernel_launch(void* const* d_in, const int* in_sizes, int n_in,
                              void* d_out, int out_size, void* d_ws, size_t ws_size,
                              hipStream_t stream) {
    const int*   y_true = (const int*)d_in[0];
    const float* y_pred = (const float*)d_in[1];
    float*       out    = (float*)d_out;
    (void)in_sizes; (void)n_in; (void)d_ws; (void)ws_size; (void)out_size;

    ctc_fwd_kernel<<<dim3(256), dim3(64), 0, stream>>>(y_true, y_pred, out);
}